// Round 2
// baseline (1548.387 us; speedup 1.0000x reference)
//
#include <hip/hip_runtime.h>
#include <hip/hip_bf16.h>

#define T_TOTAL 16384
#define D_DIM   2048
#define E_NUM   64
#define BT      32
#define DK      64
#define NKT     (D_DIM / DK)   // 32
#define CAP     256

// ---------------------------------------------------------------------------
// Fused router: logits GEMM (x·W + b) -> softmax -> argmax -> per-expert
// prob sums + counts.  One block = 32 tokens x 64 experts, 256 threads,
// grid 512 = 2 blocks/CU (2 waves/SIMD).
// x staged in LDS (double-buffered, XOR-swizzled); W streamed from global
// (16 KB k-tile stays L1-hot) via a depth-2 register pipeline.
// ---------------------------------------------------------------------------
__global__ __launch_bounds__(256, 2) void router_fused(
    const float* __restrict__ x, const float* __restrict__ W,
    const float* __restrict__ bias,
    int* __restrict__ top_idx, float* __restrict__ top_prob,
    float* __restrict__ probsum, int* __restrict__ counts)
{
    // xs4[buf][d4][tok ^ ((d4&7)<<2)] = x[tok][kt*64 + d4*4 .. +3]
    __shared__ float4 xs4[2][16][32];   // 16 KB
    __shared__ float  C[BT][68];        // 8.5 KB logits/probs tile (padded)

    const int tid = threadIdx.x;
    const int tx  = tid & 15;           // expert quad 0..15
    const int ty  = tid >> 4;           // token pair 0..15
    const int t0  = blockIdx.x * BT;

    const int st_k = tid & 15;          // staging: float4-index in k-tile
    const int st_t = tid >> 4;          // staging: token sub 0..15
    const int swz  = (st_k & 7) << 2;

    const float* xb = x + (size_t)t0 * D_DIM;
    const float* wb = W + (tx << 2);

    float acc[2][4] = {{0.f,0.f,0.f,0.f},{0.f,0.f,0.f,0.f}};

    // ---- prologue: stage k-tile 0; init W prefetch (k rows 0..7) ----
    float4 px0 = *(const float4*)(xb + (size_t)(st_t     ) * D_DIM + (st_k << 2));
    float4 px1 = *(const float4*)(xb + (size_t)(st_t + 16) * D_DIM + (st_k << 2));
    float4 bq0[4], bq1[4];
    {
        const float* p0 = wb;
        bq0[0] = *(const float4*)(p0);
        bq0[1] = *(const float4*)(p0 + E_NUM);
        bq0[2] = *(const float4*)(p0 + 2 * E_NUM);
        bq0[3] = *(const float4*)(p0 + 3 * E_NUM);
        const float* p1 = wb + 4 * E_NUM;
        bq1[0] = *(const float4*)(p1);
        bq1[1] = *(const float4*)(p1 + E_NUM);
        bq1[2] = *(const float4*)(p1 + 2 * E_NUM);
        bq1[3] = *(const float4*)(p1 + 3 * E_NUM);
    }
    xs4[0][st_k][(st_t     ) ^ swz] = px0;
    xs4[0][st_k][(st_t + 16) ^ swz] = px1;
    __syncthreads();

    for (int kt = 0; kt < NKT; ++kt) {
        const int buf = kt & 1;
        if (kt + 1 < NKT) {   // issue next x-tile loads; retire under compute
            const float* xn = xb + (size_t)(kt + 1) * DK;
            px0 = *(const float4*)(xn + (size_t)(st_t     ) * D_DIM + (st_k << 2));
            px1 = *(const float4*)(xn + (size_t)(st_t + 16) * D_DIM + (st_k << 2));
        }
#pragma unroll
        for (int kg = 0; kg < 16; ++kg) {
            const int cswz = (kg & 7) << 2;
            const float4 a0 = xs4[buf][kg][((ty << 1)    ) ^ cswz];
            const float4 a1 = xs4[buf][kg][((ty << 1) | 1) ^ cswz];
            float4 b0, b1, b2, b3;
            if ((kg & 1) == 0) { b0 = bq0[0]; b1 = bq0[1]; b2 = bq0[2]; b3 = bq0[3]; }
            else               { b0 = bq1[0]; b1 = bq1[1]; b2 = bq1[2]; b3 = bq1[3]; }

            acc[0][0] = fmaf(a0.x,b0.x, fmaf(a0.y,b1.x, fmaf(a0.z,b2.x, fmaf(a0.w,b3.x, acc[0][0]))));
            acc[0][1] = fmaf(a0.x,b0.y, fmaf(a0.y,b1.y, fmaf(a0.z,b2.y, fmaf(a0.w,b3.y, acc[0][1]))));
            acc[0][2] = fmaf(a0.x,b0.z, fmaf(a0.y,b1.z, fmaf(a0.z,b2.z, fmaf(a0.w,b3.z, acc[0][2]))));
            acc[0][3] = fmaf(a0.x,b0.w, fmaf(a0.y,b1.w, fmaf(a0.z,b2.w, fmaf(a0.w,b3.w, acc[0][3]))));
            acc[1][0] = fmaf(a1.x,b0.x, fmaf(a1.y,b1.x, fmaf(a1.z,b2.x, fmaf(a1.w,b3.x, acc[1][0]))));
            acc[1][1] = fmaf(a1.x,b0.y, fmaf(a1.y,b1.y, fmaf(a1.z,b2.y, fmaf(a1.w,b3.y, acc[1][1]))));
            acc[1][2] = fmaf(a1.x,b0.z, fmaf(a1.y,b1.z, fmaf(a1.z,b2.z, fmaf(a1.w,b3.z, acc[1][2]))));
            acc[1][3] = fmaf(a1.x,b0.w, fmaf(a1.y,b1.w, fmaf(a1.z,b2.w, fmaf(a1.w,b3.w, acc[1][3]))));

            // prefetch W rows for k-group kg+2 (wraps harmlessly at the end)
            int kpf = kt * DK + (kg << 2) + 8;
            if (kpf >= D_DIM) kpf = 0;
            const float* pp = wb + (size_t)kpf * E_NUM;
            if ((kg & 1) == 0) {
                bq0[0] = *(const float4*)(pp);
                bq0[1] = *(const float4*)(pp + E_NUM);
                bq0[2] = *(const float4*)(pp + 2 * E_NUM);
                bq0[3] = *(const float4*)(pp + 3 * E_NUM);
            } else {
                bq1[0] = *(const float4*)(pp);
                bq1[1] = *(const float4*)(pp + E_NUM);
                bq1[2] = *(const float4*)(pp + 2 * E_NUM);
                bq1[3] = *(const float4*)(pp + 3 * E_NUM);
            }
        }
        if (kt + 1 < NKT) {   // write next tile into the other buffer
            xs4[buf ^ 1][st_k][(st_t     ) ^ swz] = px0;
            xs4[buf ^ 1][st_k][(st_t + 16) ^ swz] = px1;
        }
        __syncthreads();
    }

    // ---- epilogue: bias add, write logits tile ----
    {
        const float4 bv = *(const float4*)(bias + (tx << 2));
#pragma unroll
        for (int i = 0; i < 2; ++i) {
            float4 cv;
            cv.x = acc[i][0] + bv.x;  cv.y = acc[i][1] + bv.y;
            cv.z = acc[i][2] + bv.z;  cv.w = acc[i][3] + bv.w;
            *(float4*)&C[(ty << 1) | i][tx << 2] = cv;
        }
    }
    __syncthreads();

    // ---- softmax + argmax: 8 lanes per token, experts e = q + 8*e2 ----
    {
        const int t = tid >> 3;
        const int q = tid & 7;
        float v[8];
        float m = -3.4e38f; int am = 0;
#pragma unroll
        for (int e2 = 0; e2 < 8; ++e2) {
            const float lv = C[t][q + (e2 << 3)];
            v[e2] = lv;
            if (lv > m) { m = lv; am = q + (e2 << 3); }
        }
#pragma unroll
        for (int off = 1; off < 8; off <<= 1) {
            const float om = __shfl_xor(m, off);
            const int   oa = __shfl_xor(am, off);
            if (om > m || (om == m && oa < am)) { m = om; am = oa; }
        }
        float s = 0.f;
#pragma unroll
        for (int e2 = 0; e2 < 8; ++e2) { v[e2] = __expf(v[e2] - m); s += v[e2]; }
#pragma unroll
        for (int off = 1; off < 8; off <<= 1) s += __shfl_xor(s, off);
        const float inv = 1.0f / s;   // prob of the argmax expert
#pragma unroll
        for (int e2 = 0; e2 < 8; ++e2) C[t][q + (e2 << 3)] = v[e2] * inv;
        if (q == 0) {
            top_idx[t0 + t]  = am;
            top_prob[t0 + t] = inv;
            atomicAdd(&counts[am], 1);
        }
    }
    __syncthreads();

    // ---- per-expert prob column sums (P_i numerator) ----
    if (tid < E_NUM) {
        float cs = 0.f;
#pragma unroll
        for (int r = 0; r < BT; ++r) cs += C[r][tid];
        atomicAdd(&probsum[tid], cs);
    }
}

// ---------------------------------------------------------------------------
// Capacity enforcement: block e scans all tokens in order (int4 = 4 tokens
// per lane per iter, 256/chunk); ballot prefix; uniform early-exit when full.
// ---------------------------------------------------------------------------
__global__ __launch_bounds__(64) void capacity_kernel(
    const int4* __restrict__ top_idx4, const float4* __restrict__ top_prob4,
    float* __restrict__ out)
{
    const int e    = blockIdx.x;
    const int lane = threadIdx.x;
    const unsigned long long ltm = (1ULL << lane) - 1ULL;
    int running = 0;
    for (int c = 0; c < T_TOTAL / 256; ++c) {
        const int4   iv = top_idx4[c * 64 + lane];
        const float4 pv = top_prob4[c * 64 + lane];
        const unsigned long long b0 = __ballot(iv.x == e);
        const unsigned long long b1 = __ballot(iv.y == e);
        const unsigned long long b2 = __ballot(iv.z == e);
        const unsigned long long b3 = __ballot(iv.w == e);
        const int base = c * 256 + lane * 4;
        int r = running + __popcll(b0 & ltm) + __popcll(b1 & ltm)
                        + __popcll(b2 & ltm) + __popcll(b3 & ltm); // exclusive rank of token base+0
        if (iv.x == e) { if (r < CAP) out[(size_t)(base + 0) * E_NUM + e] = pv.x; r += 1; }
        if (iv.y == e) { if (r < CAP) out[(size_t)(base + 1) * E_NUM + e] = pv.y; r += 1; }
        if (iv.z == e) { if (r < CAP) out[(size_t)(base + 2) * E_NUM + e] = pv.z; r += 1; }
        if (iv.w == e) { if (r < CAP) out[(size_t)(base + 3) * E_NUM + e] = pv.w; r += 1; }
        running += __popcll(b0) + __popcll(b1) + __popcll(b2) + __popcll(b3);
        if (running >= CAP + 64) break;   // uniform: no later token can be kept
    }
}

// ---------------------------------------------------------------------------
// Aux loss: ALPHA * E * sum_e (count_e/T)*(probsum_e/T)
// ---------------------------------------------------------------------------
__global__ __launch_bounds__(64) void aux_kernel(
    const int* __restrict__ counts, const float* __restrict__ probsum,
    float* __restrict__ out)
{
    const int e = threadIdx.x;
    float v = (counts[e] * (1.0f / T_TOTAL)) * (probsum[e] * (1.0f / T_TOTAL));
#pragma unroll
    for (int off = 32; off > 0; off >>= 1) v += __shfl_down(v, off);
    if (e == 0) out[(size_t)T_TOTAL * E_NUM] = 0.01f * 64.0f * v;
}

extern "C" void kernel_launch(void* const* d_in, const int* in_sizes, int n_in,
                              void* d_out, int out_size, void* d_ws, size_t ws_size,
                              hipStream_t stream) {
    const float* x = (const float*)d_in[0];
    const float* W = (const float*)d_in[1];
    const float* b = (const float*)d_in[2];
    float* out = (float*)d_out;
    char*  ws  = (char*)d_ws;

    int*   top_idx  = (int*)ws;                    // 16384 * 4 B
    float* top_prob = (float*)(ws + 65536);        // 16384 * 4 B
    float* probsum  = (float*)(ws + 131072);       // 64 * 4 B
    int*   counts   = (int*)(ws + 131072 + 256);   // 64 * 4 B

    hipMemsetAsync(d_out, 0, (size_t)(T_TOTAL * E_NUM + 1) * sizeof(float), stream);
    hipMemsetAsync(ws + 131072, 0, 512, stream);

    router_fused<<<T_TOTAL / BT, 256, 0, stream>>>(x, W, b, top_idx, top_prob,
                                                   probsum, counts);
    capacity_kernel<<<E_NUM, 64, 0, stream>>>((const int4*)top_idx,
                                              (const float4*)top_prob, out);
    aux_kernel<<<1, 64, 0, stream>>>(counts, probsum, out);
}

// Round 5
// 1221.547 us; speedup vs baseline: 1.2676x; 1.2676x over previous
//
#include <hip/hip_runtime.h>
#include <hip/hip_bf16.h>

#define T_TOTAL 16384
#define D_DIM   2048
#define E_NUM   64
#define BT      32
#define DK      64
#define NKT     (D_DIM / DK)   // 32
#define CAP     256

// ---------------------------------------------------------------------------
// Fused router: logits GEMM (x·W + b) -> softmax -> argmax -> per-expert
// prob sums + counts.  One block = 32 tokens x 64 experts, 256 threads,
// 2x4 thread-tile, grid 512 = 2 blocks/CU (2 waves/SIMD TLP across barriers).
// Both operands staged via LDS with constant-indexed registers only --
// round-1's register W-pipeline was demoted to scratch (3 GB spill writes,
// VALUBusy 2.5%).  Pad-17 rows: all LDS paths at structural-minimum cycles.
// ---------------------------------------------------------------------------
__global__ __launch_bounds__(256, 2) void router_fused(
    const float* __restrict__ x, const float* __restrict__ W,
    const float* __restrict__ bias,
    int* __restrict__ top_idx, float* __restrict__ top_prob,
    float* __restrict__ probsum, int* __restrict__ counts)
{
    __shared__ float4 xs4[BT][17];   // x[tok][k-quad]   8.7 KB
    __shared__ float4 ws4[DK][17];   // W[k][e-quad]    17.4 KB
    __shared__ float  C[BT][68];     // logits/probs     8.7 KB

    const int tid = threadIdx.x;
    const int tx  = tid & 15;        // expert-quad 0..15
    const int ty  = tid >> 4;        // token-pair 0..15
    const int lo4 = tid & 15;        // staging: float4 col
    const int sub = tid >> 4;        // staging: row sub 0..15
    const int t0  = blockIdx.x * BT;
    const float* xb = x + (size_t)t0 * D_DIM;

    float acc[2][4] = {{0.f,0.f,0.f,0.f},{0.f,0.f,0.f,0.f}};

    float4 px0, px1, pw[4];
    // ---- prologue: k-tile 0 global -> regs -> LDS ----
    px0 = *(const float4*)(xb + (size_t)(sub     ) * D_DIM + (lo4 << 2));
    px1 = *(const float4*)(xb + (size_t)(sub + 16) * D_DIM + (lo4 << 2));
#pragma unroll
    for (int c = 0; c < 4; ++c)
        pw[c] = *(const float4*)(W + (size_t)(c * 16 + sub) * E_NUM + (lo4 << 2));
    xs4[sub     ][lo4] = px0;
    xs4[sub + 16][lo4] = px1;
#pragma unroll
    for (int c = 0; c < 4; ++c) ws4[c * 16 + sub][lo4] = pw[c];
    __syncthreads();

    for (int kt = 0; kt < NKT; ++kt) {
        if (kt + 1 < NKT) {          // issue next-tile loads; land under compute
            const int k0 = (kt + 1) * DK;
            px0 = *(const float4*)(xb + (size_t)(sub     ) * D_DIM + k0 + (lo4 << 2));
            px1 = *(const float4*)(xb + (size_t)(sub + 16) * D_DIM + k0 + (lo4 << 2));
#pragma unroll
            for (int c = 0; c < 4; ++c)
                pw[c] = *(const float4*)(W + (size_t)(k0 + c * 16 + sub) * E_NUM + (lo4 << 2));
        }
#pragma unroll
        for (int kg = 0; kg < 16; ++kg) {
            const float4 a0 = xs4[(ty << 1)    ][kg];
            const float4 a1 = xs4[(ty << 1) | 1][kg];
            float4 b0 = ws4[(kg << 2)    ][tx];
            float4 b1 = ws4[(kg << 2) | 1][tx];
            float4 b2 = ws4[(kg << 2) | 2][tx];
            float4 b3 = ws4[(kg << 2) | 3][tx];

            acc[0][0] = fmaf(a0.x,b0.x, fmaf(a0.y,b1.x, fmaf(a0.z,b2.x, fmaf(a0.w,b3.x, acc[0][0]))));
            acc[0][1] = fmaf(a0.x,b0.y, fmaf(a0.y,b1.y, fmaf(a0.z,b2.y, fmaf(a0.w,b3.y, acc[0][1]))));
            acc[0][2] = fmaf(a0.x,b0.z, fmaf(a0.y,b1.z, fmaf(a0.z,b2.z, fmaf(a0.w,b3.z, acc[0][2]))));
            acc[0][3] = fmaf(a0.x,b0.w, fmaf(a0.y,b1.w, fmaf(a0.z,b2.w, fmaf(a0.w,b3.w, acc[0][3]))));
            acc[1][0] = fmaf(a1.x,b0.x, fmaf(a1.y,b1.x, fmaf(a1.z,b2.x, fmaf(a1.w,b3.x, acc[1][0]))));
            acc[1][1] = fmaf(a1.x,b0.y, fmaf(a1.y,b1.y, fmaf(a1.z,b2.y, fmaf(a1.w,b3.y, acc[1][1]))));
            acc[1][2] = fmaf(a1.x,b0.z, fmaf(a1.y,b1.z, fmaf(a1.z,b2.z, fmaf(a1.w,b3.z, acc[1][2]))));
            acc[1][3] = fmaf(a1.x,b0.w, fmaf(a1.y,b1.w, fmaf(a1.z,b2.w, fmaf(a1.w,b3.w, acc[1][3]))));
        }
        __syncthreads();             // all reads of this tile done
        if (kt + 1 < NKT) {
            xs4[sub     ][lo4] = px0;
            xs4[sub + 16][lo4] = px1;
#pragma unroll
            for (int c = 0; c < 4; ++c) ws4[c * 16 + sub][lo4] = pw[c];
        }
        __syncthreads();             // next tile visible
    }

    // ---- epilogue: bias add, write logits tile ----
    {
        const float4 bv = *(const float4*)(bias + (tx << 2));
#pragma unroll
        for (int i = 0; i < 2; ++i) {
            float4 cv;
            cv.x = acc[i][0] + bv.x;  cv.y = acc[i][1] + bv.y;
            cv.z = acc[i][2] + bv.z;  cv.w = acc[i][3] + bv.w;
            *(float4*)&C[(ty << 1) | i][tx << 2] = cv;
        }
    }
    __syncthreads();

    // ---- softmax + argmax: 8 lanes per token, experts e = q + 8*e2 ----
    {
        const int t = tid >> 3;      // token 0..31
        const int q = tid & 7;
        float v[8];
        float m = -3.4e38f; int am = 0;
#pragma unroll
        for (int e2 = 0; e2 < 8; ++e2) {
            const float lv = C[t][q + (e2 << 3)];
            v[e2] = lv;
            if (lv > m) { m = lv; am = q + (e2 << 3); }
        }
#pragma unroll
        for (int off = 1; off < 8; off <<= 1) {
            const float om = __shfl_xor(m, off);
            const int   oa = __shfl_xor(am, off);
            if (om > m || (om == m && oa < am)) { m = om; am = oa; }
        }
        float s = 0.f;
#pragma unroll
        for (int e2 = 0; e2 < 8; ++e2) { v[e2] = __expf(v[e2] - m); s += v[e2]; }
#pragma unroll
        for (int off = 1; off < 8; off <<= 1) s += __shfl_xor(s, off);
        const float inv = 1.0f / s;  // prob of the argmax expert
#pragma unroll
        for (int e2 = 0; e2 < 8; ++e2) C[t][q + (e2 << 3)] = v[e2] * inv;
        if (q == 0) {
            top_idx[t0 + t]  = am;
            top_prob[t0 + t] = inv;
            atomicAdd(&counts[am], 1);
        }
    }
    __syncthreads();

    // ---- per-expert prob column sums (P_i numerator): one wave, 64 lanes ----
    if (tid < E_NUM) {
        float cs = 0.f;
#pragma unroll
        for (int r = 0; r < BT; ++r) cs += C[r][tid];
        atomicAdd(&probsum[tid], cs);
    }
}

// ---------------------------------------------------------------------------
// Capacity enforcement: block e scans tokens in order (int4 = 4/lane/iter);
// ballot prefix; uniform early-exit once provably saturated.
// ---------------------------------------------------------------------------
__global__ __launch_bounds__(64) void capacity_kernel(
    const int4* __restrict__ top_idx4, const float4* __restrict__ top_prob4,
    float* __restrict__ out)
{
    const int e    = blockIdx.x;
    const int lane = threadIdx.x;
    const unsigned long long ltm = (1ULL << lane) - 1ULL;
    int running = 0;
    for (int c = 0; c < T_TOTAL / 256; ++c) {
        const int4   iv = top_idx4[c * 64 + lane];
        const float4 pv = top_prob4[c * 64 + lane];
        const unsigned long long b0 = __ballot(iv.x == e);
        const unsigned long long b1 = __ballot(iv.y == e);
        const unsigned long long b2 = __ballot(iv.z == e);
        const unsigned long long b3 = __ballot(iv.w == e);
        const int base = c * 256 + lane * 4;
        int r = running + __popcll(b0 & ltm) + __popcll(b1 & ltm)
                        + __popcll(b2 & ltm) + __popcll(b3 & ltm);
        if (iv.x == e) { if (r < CAP) out[(size_t)(base + 0) * E_NUM + e] = pv.x; r += 1; }
        if (iv.y == e) { if (r < CAP) out[(size_t)(base + 1) * E_NUM + e] = pv.y; r += 1; }
        if (iv.z == e) { if (r < CAP) out[(size_t)(base + 2) * E_NUM + e] = pv.z; r += 1; }
        if (iv.w == e) { if (r < CAP) out[(size_t)(base + 3) * E_NUM + e] = pv.w; r += 1; }
        running += __popcll(b0) + __popcll(b1) + __popcll(b2) + __popcll(b3);
        if (running >= CAP + 64) break;   // uniform; +64 guard: no kept token can follow
    }
}

// ---------------------------------------------------------------------------
// Aux loss: ALPHA * E * sum_e (count_e/T)*(probsum_e/T)
// ---------------------------------------------------------------------------
__global__ __launch_bounds__(64) void aux_kernel(
    const int* __restrict__ counts, const float* __restrict__ probsum,
    float* __restrict__ out)
{
    const int e = threadIdx.x;
    float v = (counts[e] * (1.0f / T_TOTAL)) * (probsum[e] * (1.0f / T_TOTAL));
#pragma unroll
    for (int off = 32; off > 0; off >>= 1) v += __shfl_down(v, off);
    if (e == 0) out[(size_t)T_TOTAL * E_NUM] = 0.01f * 64.0f * v;
}

extern "C" void kernel_launch(void* const* d_in, const int* in_sizes, int n_in,
                              void* d_out, int out_size, void* d_ws, size_t ws_size,
                              hipStream_t stream) {
    const float* x = (const float*)d_in[0];
    const float* W = (const float*)d_in[1];
    const float* b = (const float*)d_in[2];
    float* out = (float*)d_out;
    char*  ws  = (char*)d_ws;

    int*   top_idx  = (int*)ws;                    // 16384 * 4 B
    float* top_prob = (float*)(ws + 65536);        // 16384 * 4 B
    float* probsum  = (float*)(ws + 131072);       // 64 * 4 B
    int*   counts   = (int*)(ws + 131072 + 256);   // 64 * 4 B

    hipMemsetAsync(d_out, 0, (size_t)(T_TOTAL * E_NUM + 1) * sizeof(float), stream);
    hipMemsetAsync(ws + 131072, 0, 512, stream);

    router_fused<<<T_TOTAL / BT, 256, 0, stream>>>(x, W, b, top_idx, top_prob,
                                                   probsum, counts);
    capacity_kernel<<<E_NUM, 64, 0, stream>>>((const int4*)top_idx,
                                              (const float4*)top_prob, out);
    aux_kernel<<<1, 64, 0, stream>>>(counts, probsum, out);
}

// Round 9
// 301.999 us; speedup vs baseline: 5.1271x; 4.0449x over previous
//
#include <hip/hip_runtime.h>
#include <hip/hip_bf16.h>

#define T_TOTAL 16384
#define D_DIM   2048
#define E_NUM   64
#define BT      32
#define DK      64
#define NKT     (D_DIM / DK)   // 32
#define CAP     256

// async global->LDS, 16 B per lane; dest = wave-uniform base + lane*16
#define GLOAD16(g, l)                                                          \
    __builtin_amdgcn_global_load_lds(                                          \
        (const __attribute__((address_space(1))) unsigned int*)(g),            \
        (__attribute__((address_space(3))) unsigned int*)(l), 16, 0, 0)

// ---------------------------------------------------------------------------
// Fused router: logits GEMM (x·W + b) -> softmax -> argmax -> per-expert
// prob sums + counts.  32 tokens x 64 experts per block, 256 threads.
// Staging via global_load_lds (NO staging VGPRs -- rounds 2&5 measured
// 2.8-3.0 GB of scratch spill traffic from register staging at the
// launch_bounds 128-VGPR cap; VALUBusy 3%).  LDS double-buffered, linear
// layout (gload_lds requires it); x-tile bank conflicts fixed by both-sides
// XOR swizzle: LDS[r][c] holds x k-quad (c ^ ((r>>1)&15)), read col kg^ty
// -> conflict-free (hand-audited).  W-tile reads 2-way max (free).
// ---------------------------------------------------------------------------
__global__ __launch_bounds__(256) void router_fused(
    const float* __restrict__ x, const float* __restrict__ W,
    const float* __restrict__ bias,
    int* __restrict__ top_idx, float* __restrict__ top_prob,
    float* __restrict__ probsum, int* __restrict__ counts)
{
    __shared__ float4 xs4[2][BT][16];   // 16 KB  x[tok][k-quad], col-swizzled
    __shared__ float4 ws4[2][DK][16];   // 32 KB  W[k][e-quad], linear
    __shared__ float  C[BT][68];        // 8.7 KB logits/probs (padded rows)

    const int tid = threadIdx.x;
    const int tx  = tid & 15;           // expert-quad 0..15
    const int ty  = tid >> 4;           // token-pair 0..15
    const int w   = tid >> 6;           // wave 0..3
    const int l   = tid & 63;
    const int lr  = l >> 4;             // 0..3
    const int lc  = l & 15;
    const int t0  = blockIdx.x * BT;
    const float* xb = x + (size_t)t0 * D_DIM;

    float acc[2][4] = {{0.f,0.f,0.f,0.f},{0.f,0.f,0.f,0.f}};

    // stage k-tile kt2 into buffer b: 6 async issues per wave, no VGPRs
    auto stage = [&](int b, int kt2) {
        const int k0 = kt2 * DK;
        // W: 4 issues x 4 rows each (rows w*16+i*4 .. +3)
#pragma unroll
        for (int i = 0; i < 4; ++i) {
            const int r = w * 16 + i * 4 + lr;
            GLOAD16(W + (size_t)(k0 + r) * E_NUM + (lc << 2),
                    &ws4[b][w * 16 + i * 4][0]);
        }
        // x: 2 issues x 4 rows; source col pre-swizzled q = lc ^ ((r>>1)&15)
#pragma unroll
        for (int i = 0; i < 2; ++i) {
            const int r = w * 8 + i * 4 + lr;
            const int q = lc ^ ((r >> 1) & 15);
            GLOAD16(xb + (size_t)r * D_DIM + k0 + (q << 2),
                    &xs4[b][w * 8 + i * 4][0]);
        }
    };

    stage(0, 0);
    __syncthreads();                    // compiler drains vmcnt(0) before barrier

    int buf = 0;
    for (int kt = 0; kt < NKT; ++kt) {
        if (kt + 1 < NKT) stage(buf ^ 1, kt + 1);   // lands under compute
#pragma unroll
        for (int kg = 0; kg < 16; ++kg) {
            const int xc = kg ^ ty;     // unswizzle: k-quad kg for token pair ty
            const float4 a0 = xs4[buf][(ty << 1)    ][xc];
            const float4 a1 = xs4[buf][(ty << 1) | 1][xc];
            const float4 b0 = ws4[buf][(kg << 2)    ][tx];
            const float4 b1 = ws4[buf][(kg << 2) | 1][tx];
            const float4 b2 = ws4[buf][(kg << 2) | 2][tx];
            const float4 b3 = ws4[buf][(kg << 2) | 3][tx];

            acc[0][0] = fmaf(a0.x,b0.x, fmaf(a0.y,b1.x, fmaf(a0.z,b2.x, fmaf(a0.w,b3.x, acc[0][0]))));
            acc[0][1] = fmaf(a0.x,b0.y, fmaf(a0.y,b1.y, fmaf(a0.z,b2.y, fmaf(a0.w,b3.y, acc[0][1]))));
            acc[0][2] = fmaf(a0.x,b0.z, fmaf(a0.y,b1.z, fmaf(a0.z,b2.z, fmaf(a0.w,b3.z, acc[0][2]))));
            acc[0][3] = fmaf(a0.x,b0.w, fmaf(a0.y,b1.w, fmaf(a0.z,b2.w, fmaf(a0.w,b3.w, acc[0][3]))));
            acc[1][0] = fmaf(a1.x,b0.x, fmaf(a1.y,b1.x, fmaf(a1.z,b2.x, fmaf(a1.w,b3.x, acc[1][0]))));
            acc[1][1] = fmaf(a1.x,b0.y, fmaf(a1.y,b1.y, fmaf(a1.z,b2.y, fmaf(a1.w,b3.y, acc[1][1]))));
            acc[1][2] = fmaf(a1.x,b0.z, fmaf(a1.y,b1.z, fmaf(a1.z,b2.z, fmaf(a1.w,b3.z, acc[1][2]))));
            acc[1][3] = fmaf(a1.x,b0.w, fmaf(a1.y,b1.w, fmaf(a1.z,b2.w, fmaf(a1.w,b3.w, acc[1][3]))));
        }
        __syncthreads();   // drains vmcnt (stage done) + all waves done reading buf
        buf ^= 1;
    }

    // ---- epilogue: bias add, write logits tile ----
    {
        const float4 bv = *(const float4*)(bias + (tx << 2));
#pragma unroll
        for (int i = 0; i < 2; ++i) {
            float4 cv;
            cv.x = acc[i][0] + bv.x;  cv.y = acc[i][1] + bv.y;
            cv.z = acc[i][2] + bv.z;  cv.w = acc[i][3] + bv.w;
            *(float4*)&C[(ty << 1) | i][tx << 2] = cv;
        }
    }
    __syncthreads();

    // ---- softmax + argmax: 8 lanes per token, experts e = q + 8*e2 ----
    {
        const int t = tid >> 3;      // token 0..31
        const int q = tid & 7;
        float v[8];
        float m = -3.4e38f; int am = 0;
#pragma unroll
        for (int e2 = 0; e2 < 8; ++e2) {
            const float lv = C[t][q + (e2 << 3)];
            v[e2] = lv;
            if (lv > m) { m = lv; am = q + (e2 << 3); }
        }
#pragma unroll
        for (int off = 1; off < 8; off <<= 1) {
            const float om = __shfl_xor(m, off);
            const int   oa = __shfl_xor(am, off);
            if (om > m || (om == m && oa < am)) { m = om; am = oa; }
        }
        float s = 0.f;
#pragma unroll
        for (int e2 = 0; e2 < 8; ++e2) { v[e2] = __expf(v[e2] - m); s += v[e2]; }
#pragma unroll
        for (int off = 1; off < 8; off <<= 1) s += __shfl_xor(s, off);
        const float inv = 1.0f / s;  // prob of the argmax expert
#pragma unroll
        for (int e2 = 0; e2 < 8; ++e2) C[t][q + (e2 << 3)] = v[e2] * inv;
        if (q == 0) {
            top_idx[t0 + t]  = am;
            top_prob[t0 + t] = inv;
            atomicAdd(&counts[am], 1);
        }
    }
    __syncthreads();

    // ---- per-expert prob column sums (P_i numerator): one wave, 64 lanes ----
    if (tid < E_NUM) {
        float cs = 0.f;
#pragma unroll
        for (int r = 0; r < BT; ++r) cs += C[r][tid];
        atomicAdd(&probsum[tid], cs);
    }
}

// ---------------------------------------------------------------------------
// Capacity enforcement: block e scans tokens in order (int4 = 4/lane/iter);
// ballot prefix; uniform early-exit once provably saturated.
// ---------------------------------------------------------------------------
__global__ __launch_bounds__(64) void capacity_kernel(
    const int4* __restrict__ top_idx4, const float4* __restrict__ top_prob4,
    float* __restrict__ out)
{
    const int e    = blockIdx.x;
    const int lane = threadIdx.x;
    const unsigned long long ltm = (1ULL << lane) - 1ULL;
    int running = 0;
    for (int c = 0; c < T_TOTAL / 256; ++c) {
        const int4   iv = top_idx4[c * 64 + lane];
        const float4 pv = top_prob4[c * 64 + lane];
        const unsigned long long b0 = __ballot(iv.x == e);
        const unsigned long long b1 = __ballot(iv.y == e);
        const unsigned long long b2 = __ballot(iv.z == e);
        const unsigned long long b3 = __ballot(iv.w == e);
        const int base = c * 256 + lane * 4;
        int r = running + __popcll(b0 & ltm) + __popcll(b1 & ltm)
                        + __popcll(b2 & ltm) + __popcll(b3 & ltm);
        if (iv.x == e) { if (r < CAP) out[(size_t)(base + 0) * E_NUM + e] = pv.x; r += 1; }
        if (iv.y == e) { if (r < CAP) out[(size_t)(base + 1) * E_NUM + e] = pv.y; r += 1; }
        if (iv.z == e) { if (r < CAP) out[(size_t)(base + 2) * E_NUM + e] = pv.z; r += 1; }
        if (iv.w == e) { if (r < CAP) out[(size_t)(base + 3) * E_NUM + e] = pv.w; r += 1; }
        running += __popcll(b0) + __popcll(b1) + __popcll(b2) + __popcll(b3);
        if (running >= CAP + 64) break;   // uniform; +64 guard: no kept token can follow
    }
}

// ---------------------------------------------------------------------------
// Aux loss: ALPHA * E * sum_e (count_e/T)*(probsum_e/T)
// ---------------------------------------------------------------------------
__global__ __launch_bounds__(64) void aux_kernel(
    const int* __restrict__ counts, const float* __restrict__ probsum,
    float* __restrict__ out)
{
    const int e = threadIdx.x;
    float v = (counts[e] * (1.0f / T_TOTAL)) * (probsum[e] * (1.0f / T_TOTAL));
#pragma unroll
    for (int off = 32; off > 0; off >>= 1) v += __shfl_down(v, off);
    if (e == 0) out[(size_t)T_TOTAL * E_NUM] = 0.01f * 64.0f * v;
}

extern "C" void kernel_launch(void* const* d_in, const int* in_sizes, int n_in,
                              void* d_out, int out_size, void* d_ws, size_t ws_size,
                              hipStream_t stream) {
    const float* x = (const float*)d_in[0];
    const float* W = (const float*)d_in[1];
    const float* b = (const float*)d_in[2];
    float* out = (float*)d_out;
    char*  ws  = (char*)d_ws;

    int*   top_idx  = (int*)ws;                    // 16384 * 4 B
    float* top_prob = (float*)(ws + 65536);        // 16384 * 4 B
    float* probsum  = (float*)(ws + 131072);       // 64 * 4 B
    int*   counts   = (int*)(ws + 131072 + 256);   // 64 * 4 B

    hipMemsetAsync(d_out, 0, (size_t)(T_TOTAL * E_NUM + 1) * sizeof(float), stream);
    hipMemsetAsync(ws + 131072, 0, 512, stream);

    router_fused<<<T_TOTAL / BT, 256, 0, stream>>>(x, W, b, top_idx, top_prob,
                                                   probsum, counts);
    capacity_kernel<<<E_NUM, 64, 0, stream>>>((const int4*)top_idx,
                                              (const float4*)top_prob, out);
    aux_kernel<<<1, 64, 0, stream>>>(counts, probsum, out);
}